// Round 1
// baseline (126.633 us; speedup 1.0000x reference)
//
#include <hip/hip_runtime.h>
#include <math.h>

#define HH 128
#define WW 128
#define NG 2048
#define DIMV 768
#define PIX (HH * WW)
#define A_MIN (1.0f / 255.0f)
#define TW 16
#define TH 4
#define NT 512            // threads per block (8 waves)
#define NWV 8
#define CH 256            // survivor chunk size held in LDS
#define TWO_PI 6.28318530717958647692f

// ---------------------------------------------------------------------------
// Single fused kernel: one 16x4 pixel tile per block (256 blocks = 1/CU,
// 512 threads = 8 waves).
//  Phase B: cull all 2048 gaussians vs tile rect using REGISTER-ONLY lite
//           params (gx,gy via 2 exp; r2 via log — no trig, no LDS tables).
//           Exact-conservative bound: alpha>=1/255 requires
//           sigma <= ln(255*op); sigma >= |d|^2/(2*lmax); lmax < cxx+cyy
//           = s0^2+s1^2 (rotation-invariant -> no sin/cos needed to cull).
//  Phase P: full conic/color ONLY for survivors (~40/tile vs 2048),
//           chunk-compacted into 10 KB of LDS.
//  Phase C: 8-way wave split over survivors, 1 pixel/lane, LDS broadcast.
//  Phase D: cross-wave reduce, clip -> tile rgb in LDS.
//  Phase E: in-block expansion to 768 channels + direct stores (no img
//           intermediate, no second launch, no global barrier). Stores are
//           64B-aligned row chunks; 196 KB/block, 50.3 MB total.
// ---------------------------------------------------------------------------
__global__ __launch_bounds__(NT) void fused_kernel(
    const float* __restrict__ xyz, const float* __restrict__ scaling,
    const float* __restrict__ rotation, const float* __restrict__ features,
    const float* __restrict__ opacity, const float* __restrict__ w_up,
    const float* __restrict__ b_up, float* __restrict__ out)
{
    __shared__ int s_cnt;
    __shared__ int s_idx[NG];
    __shared__ float4 cA[CH];                 // (A/2, B, C/2, op)
    __shared__ float4 cB[CH];                 // (gx, gy, f0, f1)
    __shared__ float2 cC[CH];                 // (f2, -)
    __shared__ float s_red[NWV * 64 * 3];
    __shared__ __align__(16) float s_r[64];
    __shared__ __align__(16) float s_g[64];
    __shared__ __align__(16) float s_b[64];

    int tid = threadIdx.x;
    int bx = blockIdx.x & 7, by = blockIdx.x >> 3;
    int px0 = bx * TW, py0 = by * TH;

    if (tid == 0) s_cnt = 0;
    __syncthreads();

    // ---- Phase B: cull with register-only lite params
    {
        float x0 = px0 + 0.5f, x1 = px0 + TW - 0.5f;
        float y0 = py0 + 0.5f, y1 = py0 + TH - 0.5f;
        #pragma unroll
        for (int g0 = 0; g0 < NG; g0 += NT) {
            int g = g0 + tid;
            float2 xz = ((const float2*)xyz)[g];
            float e2x = __expf(2.0f * xz.x);
            float e2y = 2.0f * __expf(2.0f * xz.y);
            float gx = (e2x / (e2x + 1.0f)) * (float)WW;   // 0.5*(tanh+1)*W
            float gy = (e2y / (e2y + 2.0f)) * (float)HH;
            float2 sc = ((const float2*)scaling)[g];
            float s0 = fabsf(sc.x + 0.5f);
            float s1 = fabsf(sc.y + 0.5f);
            float trc = s0 * s0 + s1 * s1;                 // > lmax of cov
            float L = __logf(255.0f * opacity[g]);
            float r2 = (L > 0.0f) ? 2.0f * L * trc * 1.0002f + 1e-3f : -1.0f;
            float ddx = fmaxf(fmaxf(x0 - gx, gx - x1), 0.0f);
            float ddy = fmaxf(fmaxf(y0 - gy, gy - y1), 0.0f);
            if (ddx * ddx + ddy * ddy <= r2) {
                int pos = atomicAdd(&s_cnt, 1);
                s_idx[pos] = g;
            }
        }
    }
    __syncthreads();
    int cnt = s_cnt;

    int lane = tid & 63, wv = tid >> 6;
    float pxf = px0 + (lane & 15) + 0.5f;
    float pyf = py0 + (lane >> 4) + 0.5f;
    float ar = 0.0f, ag = 0.0f, ab = 0.0f;

    // ---- chunked: full params for survivors only, then accumulate
    for (int ck = 0; ck < cnt; ck += CH) {
        int csz = min(CH, cnt - ck);
        for (int j = tid; j < csz; j += NT) {
            int g = s_idx[ck + j];
            float2 xz = ((const float2*)xyz)[g];
            float e2x = __expf(2.0f * xz.x);
            float e2y = 2.0f * __expf(2.0f * xz.y);
            float gx = (e2x / (e2x + 1.0f)) * (float)WW;
            float gy = (e2y / (e2y + 2.0f)) * (float)HH;
            float2 sc = ((const float2*)scaling)[g];
            float s0 = fabsf(sc.x + 0.5f);
            float s1 = fabsf(sc.y + 0.5f);
            float th = TWO_PI / (1.0f + __expf(-rotation[g]));
            float sn = __sinf(th), cs = __cosf(th);
            float a = cs * s0, b = -sn * s1, d = sn * s0, e = cs * s1;
            float cxx = a * a + b * b;
            float cxy = a * d + b * e;
            float cyy = d * d + e * e;
            float inv = 1.0f / (cxx * cyy - cxy * cxy);  // det >= 1/16
            float op = opacity[g];
            cA[j] = make_float4(0.5f * cyy * inv, -cxy * inv, 0.5f * cxx * inv, op);
            cB[j] = make_float4(gx, gy, features[3 * g + 0], features[3 * g + 1]);
            cC[j] = make_float2(features[3 * g + 2], 0.0f);
        }
        __syncthreads();
        for (int k = wv; k < csz; k += NWV) {
            float4 a0 = cA[k];
            float4 a1 = cB[k];
            float2 a2 = cC[k];
            float dx = a1.x - pxf, dy = a1.y - pyf;
            float sig = fmaf(a0.y * dx, dy, fmaf(a0.x * dx, dx, a0.z * dy * dy));
            float al = fminf(0.999f, a0.w * __expf(-sig));
            al = (sig < 0.0f || al < A_MIN) ? 0.0f : al;
            ar = fmaf(al, a1.z, ar);
            ag = fmaf(al, a1.w, ag);
            ab = fmaf(al, a2.x, ab);
        }
        __syncthreads();   // protect cA/cB/cC before next chunk overwrites
    }

    // ---- Phase D: cross-wave reduce, clip -> tile rgb
    s_red[(wv * 64 + lane) * 3 + 0] = ar;
    s_red[(wv * 64 + lane) * 3 + 1] = ag;
    s_red[(wv * 64 + lane) * 3 + 2] = ab;
    __syncthreads();
    if (tid < 64) {
        float sr = 0.0f, sg = 0.0f, sb = 0.0f;
        #pragma unroll
        for (int w = 0; w < NWV; ++w) {
            sr += s_red[(w * 64 + tid) * 3 + 0];
            sg += s_red[(w * 64 + tid) * 3 + 1];
            sb += s_red[(w * 64 + tid) * 3 + 2];
        }
        s_r[tid] = fminf(1.0f, fmaxf(0.0f, sr));
        s_g[tid] = fminf(1.0f, fmaxf(0.0f, sg));
        s_b[tid] = fminf(1.0f, fmaxf(0.0f, sb));
    }
    __syncthreads();

    // ---- Phase E: expand to 768 channels, store directly.
    // t -> quad q (4 consecutive px) + channel base; d = dbase + 32*i.
    // Lanes 0..15 of a wave share dbase -> per store: 4x 64B aligned chunks.
    int q = tid & 15, dbase = tid >> 4;          // dbase in [0,32)
    int row = q >> 2, c4 = q & 3;
    float4 r4 = *(const float4*)&s_r[row * 16 + c4 * 4];
    float4 g4 = *(const float4*)&s_g[row * 16 + c4 * 4];
    float4 b4 = *(const float4*)&s_b[row * 16 + c4 * 4];
    size_t pofs = (size_t)(py0 + row) * WW + px0 + c4 * 4;
    for (int i = 0; i < DIMV / 32; ++i) {        // 24 iterations
        int d = dbase + (i << 5);
        float w0 = w_up[3 * d + 0], w1 = w_up[3 * d + 1], w2 = w_up[3 * d + 2];
        float bb = b_up[d];
        float4 v;
        v.x = fmaf(w0, r4.x, fmaf(w1, g4.x, fmaf(w2, b4.x, bb)));
        v.y = fmaf(w0, r4.y, fmaf(w1, g4.y, fmaf(w2, b4.y, bb)));
        v.z = fmaf(w0, r4.z, fmaf(w1, g4.z, fmaf(w2, b4.z, bb)));
        v.w = fmaf(w0, r4.w, fmaf(w1, g4.w, fmaf(w2, b4.w, bb)));
        *(float4*)(out + (size_t)d * PIX + pofs) = v;
    }
}

extern "C" void kernel_launch(void* const* d_in, const int* in_sizes, int n_in,
                              void* d_out, int out_size, void* d_ws, size_t ws_size,
                              hipStream_t stream)
{
    // setup_inputs order: x(unused), xyz, scaling, rotation, features, opacity, w_up, b_up
    const float* xyz      = (const float*)d_in[1];
    const float* scaling  = (const float*)d_in[2];
    const float* rotation = (const float*)d_in[3];
    const float* features = (const float*)d_in[4];
    const float* opacity  = (const float*)d_in[5];
    const float* w_up     = (const float*)d_in[6];
    const float* b_up     = (const float*)d_in[7];
    (void)d_ws; (void)ws_size;

    fused_kernel<<<256, NT, 0, stream>>>(xyz, scaling, rotation, features,
                                         opacity, w_up, b_up, (float*)d_out);
}

// Round 2
// 109.248 us; speedup vs baseline: 1.1591x; 1.1591x over previous
//
#include <hip/hip_runtime.h>
#include <math.h>

#define HH 128
#define WW 128
#define NG 2048
#define DIMV 768
#define PIX (HH * WW)
#define A_MIN (1.0f / 255.0f)
#define TW 16
#define TH 4
#define NT 512            // raster threads per block (8 waves)
#define NWV 8
#define CH 256            // survivor chunk size held in LDS
#define TWO_PI 6.28318530717958647692f

// ---------------------------------------------------------------------------
// K1 (raster): one 16x4 pixel tile per block (256 blocks, 512 threads).
//  Phase B: cull all 2048 gaussians vs tile rect using REGISTER-ONLY lite
//           params (gx,gy via 2 exp; r2 via log — no trig, no LDS tables).
//           Exact-conservative bound: alpha>=1/255 requires
//           sigma <= ln(255*op); sigma >= |d|^2/(2*lmax); lmax <= cxx+cyy
//           = s0^2+s1^2 (trace is rotation-invariant -> no sin/cos to cull).
//  Phase P: full conic/color ONLY for survivors (~45/tile vs 2048),
//           chunk-compacted into 10 KB of LDS.
//  Phase C: 8-way wave split over survivors, 1 pixel/lane, LDS broadcast.
//  Phase D: cross-wave reduce, clip, store img planes (r,g,b) to ws
//           (192 KB total -> L2-resident for K2).
// ---------------------------------------------------------------------------
__global__ __launch_bounds__(NT) void raster_kernel(
    const float* __restrict__ xyz, const float* __restrict__ scaling,
    const float* __restrict__ rotation, const float* __restrict__ features,
    const float* __restrict__ opacity, float* __restrict__ img)
{
    __shared__ int s_cnt;
    __shared__ int s_idx[NG];
    __shared__ float4 cA[CH];                 // (A/2, B, C/2, op)
    __shared__ float4 cB[CH];                 // (gx, gy, f0, f1)
    __shared__ float2 cC[CH];                 // (f2, -)
    __shared__ float s_red[NWV * 64 * 3];

    int tid = threadIdx.x;
    int bx = blockIdx.x & 7, by = blockIdx.x >> 3;
    int px0 = bx * TW, py0 = by * TH;

    if (tid == 0) s_cnt = 0;
    __syncthreads();

    // ---- Phase B: cull with register-only lite params (no trig)
    {
        float x0 = px0 + 0.5f, x1 = px0 + TW - 0.5f;
        float y0 = py0 + 0.5f, y1 = py0 + TH - 0.5f;
        #pragma unroll
        for (int g0 = 0; g0 < NG; g0 += NT) {
            int g = g0 + tid;
            float2 xz = ((const float2*)xyz)[g];
            float e2x = __expf(2.0f * xz.x);
            float e2y = 2.0f * __expf(2.0f * xz.y);
            float gx = (e2x / (e2x + 1.0f)) * (float)WW;   // 0.5*(tanh+1)*W
            float gy = (e2y / (e2y + 2.0f)) * (float)HH;
            float2 sc = ((const float2*)scaling)[g];
            float s0 = fabsf(sc.x + 0.5f);
            float s1 = fabsf(sc.y + 0.5f);
            float trc = s0 * s0 + s1 * s1;                 // >= lmax of cov
            float L = __logf(255.0f * opacity[g]);
            float r2 = (L > 0.0f) ? 2.0f * L * trc * 1.0002f + 1e-3f : -1.0f;
            float ddx = fmaxf(fmaxf(x0 - gx, gx - x1), 0.0f);
            float ddy = fmaxf(fmaxf(y0 - gy, gy - y1), 0.0f);
            if (ddx * ddx + ddy * ddy <= r2) {
                int pos = atomicAdd(&s_cnt, 1);
                s_idx[pos] = g;
            }
        }
    }
    __syncthreads();
    int cnt = s_cnt;

    int lane = tid & 63, wv = tid >> 6;
    float pxf = px0 + (lane & 15) + 0.5f;
    float pyf = py0 + (lane >> 4) + 0.5f;
    float ar = 0.0f, ag = 0.0f, ab = 0.0f;

    // ---- survivors only: full params into LDS chunk, then accumulate
    for (int ck = 0; ck < cnt; ck += CH) {
        int csz = min(CH, cnt - ck);
        for (int j = tid; j < csz; j += NT) {
            int g = s_idx[ck + j];
            float2 xz = ((const float2*)xyz)[g];
            float e2x = __expf(2.0f * xz.x);
            float e2y = 2.0f * __expf(2.0f * xz.y);
            float gx = (e2x / (e2x + 1.0f)) * (float)WW;
            float gy = (e2y / (e2y + 2.0f)) * (float)HH;
            float2 sc = ((const float2*)scaling)[g];
            float s0 = fabsf(sc.x + 0.5f);
            float s1 = fabsf(sc.y + 0.5f);
            float th = TWO_PI / (1.0f + __expf(-rotation[g]));
            float sn = __sinf(th), cs = __cosf(th);
            float a = cs * s0, b = -sn * s1, d = sn * s0, e = cs * s1;
            float cxx = a * a + b * b;
            float cxy = a * d + b * e;
            float cyy = d * d + e * e;
            float inv = 1.0f / (cxx * cyy - cxy * cxy);  // det >= 1/16
            float op = opacity[g];
            cA[j] = make_float4(0.5f * cyy * inv, -cxy * inv, 0.5f * cxx * inv, op);
            cB[j] = make_float4(gx, gy, features[3 * g + 0], features[3 * g + 1]);
            cC[j] = make_float2(features[3 * g + 2], 0.0f);
        }
        __syncthreads();
        for (int k = wv; k < csz; k += NWV) {   // k is wave-uniform -> broadcast
            float4 a0 = cA[k];
            float4 a1 = cB[k];
            float2 a2 = cC[k];
            float dx = a1.x - pxf, dy = a1.y - pyf;
            float sig = fmaf(a0.y * dx, dy, fmaf(a0.x * dx, dx, a0.z * dy * dy));
            float al = fminf(0.999f, a0.w * __expf(-sig));
            al = (sig < 0.0f || al < A_MIN) ? 0.0f : al;
            ar = fmaf(al, a1.z, ar);
            ag = fmaf(al, a1.w, ag);
            ab = fmaf(al, a2.x, ab);
        }
        __syncthreads();   // protect chunk before overwrite
    }

    // ---- Phase D: reduce across waves, clip, store img planes
    s_red[(wv * 64 + lane) * 3 + 0] = ar;
    s_red[(wv * 64 + lane) * 3 + 1] = ag;
    s_red[(wv * 64 + lane) * 3 + 2] = ab;
    __syncthreads();
    if (tid < 64) {
        float sr = 0.0f, sg = 0.0f, sb = 0.0f;
        #pragma unroll
        for (int w = 0; w < NWV; ++w) {
            sr += s_red[(w * 64 + tid) * 3 + 0];
            sg += s_red[(w * 64 + tid) * 3 + 1];
            sb += s_red[(w * 64 + tid) * 3 + 2];
        }
        int p = (py0 + (tid >> 4)) * WW + px0 + (tid & 15);
        img[p]           = fminf(1.0f, fmaxf(0.0f, sr));
        img[PIX + p]     = fminf(1.0f, fmaxf(0.0f, sg));
        img[2 * PIX + p] = fminf(1.0f, fmaxf(0.0f, sb));
    }
}

// ---------------------------------------------------------------------------
// K2: projection to 768 channels. 3072 blocks (12/CU): blockIdx = grp*16+seg,
// grp -> 4 consecutive channels, seg -> 1024-pixel span. Pure write-bound:
// 3x float4 L2-resident img reads, 16 FMA, 4x float4 coalesced stores
// (4 KB contiguous per channel segment -> full cachelines).
// ---------------------------------------------------------------------------
__global__ __launch_bounds__(256) void project_kernel(
    const float* __restrict__ img, const float* __restrict__ w_up,
    const float* __restrict__ b_up, float* __restrict__ out)
{
    int grp = blockIdx.x >> 4;
    int seg = blockIdx.x & 15;
    int p = seg * 1024 + threadIdx.x * 4;
    float4 r = *(const float4*)(img + p);
    float4 g = *(const float4*)(img + PIX + p);
    float4 b = *(const float4*)(img + 2 * PIX + p);
    int d0 = grp * 4;
    #pragma unroll
    for (int i = 0; i < 4; ++i) {
        int d = d0 + i;
        float w0 = w_up[3 * d + 0], w1 = w_up[3 * d + 1], w2 = w_up[3 * d + 2];
        float bb = b_up[d];
        float4 v;
        v.x = fmaf(w0, r.x, fmaf(w1, g.x, fmaf(w2, b.x, bb)));
        v.y = fmaf(w0, r.y, fmaf(w1, g.y, fmaf(w2, b.y, bb)));
        v.z = fmaf(w0, r.z, fmaf(w1, g.z, fmaf(w2, b.z, bb)));
        v.w = fmaf(w0, r.w, fmaf(w1, g.w, fmaf(w2, b.w, bb)));
        *(float4*)(out + (size_t)d * PIX + p) = v;
    }
}

extern "C" void kernel_launch(void* const* d_in, const int* in_sizes, int n_in,
                              void* d_out, int out_size, void* d_ws, size_t ws_size,
                              hipStream_t stream)
{
    // setup_inputs order: x(unused), xyz, scaling, rotation, features, opacity, w_up, b_up
    const float* xyz      = (const float*)d_in[1];
    const float* scaling  = (const float*)d_in[2];
    const float* rotation = (const float*)d_in[3];
    const float* features = (const float*)d_in[4];
    const float* opacity  = (const float*)d_in[5];
    const float* w_up     = (const float*)d_in[6];
    const float* b_up     = (const float*)d_in[7];
    float* out = (float*)d_out;
    float* img = (float*)d_ws;   // 3 planes of PIX floats (192 KB, L2-resident)

    raster_kernel<<<256, NT, 0, stream>>>(xyz, scaling, rotation, features,
                                          opacity, img);
    project_kernel<<<(DIMV / 4) * 16, 256, 0, stream>>>(img, w_up, b_up, out);
}